// Round 1
// 450.254 us; speedup vs baseline: 1.0296x; 1.0296x over previous
//
#include <hip/hip_runtime.h>
#include <hip/hip_bf16.h>

// Problem constants (shapes fixed by the reference)
#define DIM 256          // feature dim (D == H == 256)
#define KDIM 512         // fused K = D(agg) + D(root)

typedef unsigned short ushort_t;
typedef __attribute__((ext_vector_type(8))) short short8;   // 8 x bf16 (4 VGPRs) MFMA A/B frag
typedef __attribute__((ext_vector_type(4))) float f32x4;    // MFMA C/D frag

__device__ __forceinline__ float bf2f(ushort_t u) {
    union { unsigned int i; float f; } c; c.i = ((unsigned int)u) << 16; return c.f;
}
__device__ __forceinline__ ushort_t f2bf(float f) {
    unsigned int x = __float_as_uint(f);
    unsigned int r = (x + 0x7fffu + ((x >> 16) & 1u)) >> 16;
    return (ushort_t)r;
}

// async global->LDS, 16B/lane; LDS dest = wave-uniform base + lane*16
__device__ __forceinline__ void gload_lds16(const ushort_t* g, ushort_t* l) {
    __builtin_amdgcn_global_load_lds(
        (const __attribute__((address_space(1))) unsigned int*)g,
        (__attribute__((address_space(3))) unsigned int*)l, 16, 0, 0);
}

// ---------------- edge_index dtype probe (ONCE; flag read is scalar thereafter) ----------------
__global__ void detect_kernel(const int* __restrict__ ei, int* __restrict__ flag) {
    __shared__ int any;
    if (threadIdx.x == 0) any = 0;
    __syncthreads();
    if (ei[2 * threadIdx.x + 1] != 0) atomicOr(&any, 1);
    __syncthreads();
    if (threadIdx.x == 0) *flag = (any == 0) ? 1 : 0;   // 1 => int64 layout
}

// ---------------- prep: convert x->bf16 | pack 3 weight sets (frag tiles) | histogram ----------------
// B pack layout per layer: Bp[ks][nt][lane][h]  (16*16*64*8 halves = 256 KB)
//   n = nt*16 + (lane&15),  k = ks*32 + (lane>>4)*8 + h
// => wave B-frag (ks, nt) is ONE contiguous 1KB block, coalesced global->VGPR.
// Histogram branch: 4 edges/thread, coalesced int4 loads, 4 independent atomics.

__global__ __launch_bounds__(256)
void prep_kernel(const float* __restrict__ x, ushort_t* __restrict__ xb, int n4, int cb,
                 const float* __restrict__ W0r, const float* __restrict__ W0o,
                 const float* __restrict__ W1r, const float* __restrict__ W1o,
                 const float* __restrict__ W2r, const float* __restrict__ W2o,
                 ushort_t* __restrict__ Wt, int pb,
                 const int* __restrict__ ei, const int* __restrict__ flag,
                 int* __restrict__ deg, int E, int Nn) {
    int bid = blockIdx.x;
    int t = threadIdx.x;
    if (bid < cb) {
        int i = bid * 256 + t;
        if (i < n4) {
            const float4 v = *(const float4*)(x + (size_t)i * 4);
            ushort4 o;
            o.x = f2bf(v.x); o.y = f2bf(v.y); o.z = f2bf(v.z); o.w = f2bf(v.w);
            *(ushort4*)(xb + (size_t)i * 4) = o;
        }
    } else if (bid < cb + pb) {
        int id = (bid - cb) * 256 + t;            // over 3*131072
        int layer = id >> 17;
        int rem = id & 131071;
        int ks   = rem >> 13;                     // 8192 per ks
        int nt   = (rem >> 9) & 15;
        int lane = (rem >> 3) & 63;
        int h    = rem & 7;
        int n = nt * 16 + (lane & 15);
        int k = ks * 32 + ((lane >> 4) << 3) + h;
        const float* Wr = (layer == 0) ? W0r : (layer == 1) ? W1r : W2r;
        const float* Wo = (layer == 0) ? W0o : (layer == 1) ? W1o : W2o;
        float v = (k < DIM) ? Wr[k * DIM + n] : Wo[(k - DIM) * DIM + n];
        Wt[id] = f2bf(v);
    } else {
        int q = (bid - cb - pb) * 256 + t;        // quad index: 4 edges each
        int e0 = q * 4;
        if (e0 < E) {
            const int is64 = *flag;               // wave-uniform scalar load
            const int n = (E - e0 < 4) ? (E - e0) : 4;
            int d[4];
            if (is64) {
                if (n == 4 && (E & 1) == 0) {
                    const int4 c = *(const int4*)(ei + 2 * (size_t)(E + e0));
                    const int4 f = *(const int4*)(ei + 2 * (size_t)(E + e0) + 4);
                    d[0] = c.x; d[1] = c.z; d[2] = f.x; d[3] = f.z;
                } else {
                    for (int i = 0; i < 4; ++i) d[i] = (i < n) ? ei[2 * (size_t)(E + e0 + i)] : 0;
                }
            } else {
                if (n == 4 && (E & 3) == 0) {
                    const int4 c = *(const int4*)(ei + E + e0);
                    d[0] = c.x; d[1] = c.y; d[2] = c.z; d[3] = c.w;
                } else {
                    for (int i = 0; i < 4; ++i) d[i] = (i < n) ? ei[E + e0 + i] : 0;
                }
            }
#pragma unroll
            for (int i = 0; i < 4; ++i) {
                if (i < n) {
                    int dd = d[i]; dd = (dd < 0) ? 0 : (dd >= Nn ? Nn - 1 : dd);
                    atomicAdd(&deg[dd], 1);
                }
            }
        }
    }
}

// ---------------- scan: deg -> row_ptr/cursor (2 kernels) ----------------

__global__ __launch_bounds__(256)
void scan1_kernel(const int* __restrict__ deg, int* __restrict__ partials, int Nn) {
    __shared__ int red[256];
    int t = threadIdx.x;
    int base = blockIdx.x * 1024 + t * 4;
    int s = 0;
    if (base + 3 < Nn) {
        const int4 v = *(const int4*)(deg + base);
        s = v.x + v.y + v.z + v.w;
    } else {
        for (int i = 0; i < 4; ++i) if (base + i < Nn) s += deg[base + i];
    }
    red[t] = s;
    __syncthreads();
    for (int off = 128; off > 0; off >>= 1) {
        if (t < off) red[t] += red[t + off];
        __syncthreads();
    }
    if (t == 0) partials[blockIdx.x] = red[0];
}

__global__ __launch_bounds__(256)
void scan3_kernel(const int* __restrict__ deg, const int* __restrict__ partials,
                  int* __restrict__ row_ptr, int* __restrict__ cursor, int Nn, int E) {
    __shared__ int sdata[256];
    int t = threadIdx.x;
    int pref = 0;
    for (int i = 0; i < blockIdx.x; ++i) pref += partials[i];   // <=49 L2-hot loads
    int base = blockIdx.x * 1024 + t * 4;
    int d0 = 0, d1 = 0, d2 = 0, d3 = 0;
    if (base + 3 < Nn) {
        const int4 v = *(const int4*)(deg + base);
        d0 = v.x; d1 = v.y; d2 = v.z; d3 = v.w;
    } else {
        if (base + 0 < Nn) d0 = deg[base + 0];
        if (base + 1 < Nn) d1 = deg[base + 1];
        if (base + 2 < Nn) d2 = deg[base + 2];
        if (base + 3 < Nn) d3 = deg[base + 3];
    }
    int tsum = d0 + d1 + d2 + d3;
    sdata[t] = tsum;
    __syncthreads();
    for (int off = 1; off < 256; off <<= 1) {
        int u = (t >= off) ? sdata[t - off] : 0;
        __syncthreads();
        sdata[t] += u;
        __syncthreads();
    }
    int p0 = sdata[t] - tsum + pref;
    int p1 = p0 + d0, p2 = p1 + d1, p3 = p2 + d2;
    if (base + 3 < Nn) {
        *(int4*)(row_ptr + base) = make_int4(p0, p1, p2, p3);
        *(int4*)(cursor  + base) = make_int4(p0, p1, p2, p3);
    } else {
        if (base + 0 < Nn) { row_ptr[base + 0] = p0; cursor[base + 0] = p0; }
        if (base + 1 < Nn) { row_ptr[base + 1] = p1; cursor[base + 1] = p1; }
        if (base + 2 < Nn) { row_ptr[base + 2] = p2; cursor[base + 2] = p2; }
        if (base + 3 < Nn) { row_ptr[base + 3] = p3; cursor[base + 3] = p3; }
    }
    if (blockIdx.x == 0 && t == 0) row_ptr[Nn] = E;
}

// ---------------- fill: 4 edges/thread, int4-coalesced ei loads, uint16 srcs ----------------
// srcs as uint16 (N=50000 < 65536): halves the random-scatter dirty-line traffic
// (WRITE_SIZE was 16x-amplified 4B scatters). 4 independent atomicAdds per thread
// overlap the return latency that previously serialized one-per-thread.

__global__ __launch_bounds__(256)
void fill_kernel(const int* __restrict__ ei, const int* __restrict__ flag,
                 int* __restrict__ cursor, ushort_t* __restrict__ srcs, int E, int Nn) {
    int q = blockIdx.x * blockDim.x + threadIdx.x;
    int e0 = q * 4;
    if (e0 >= E) return;
    const int is64 = *flag;                       // wave-uniform scalar load
    const int n = (E - e0 < 4) ? (E - e0) : 4;
    int s[4], d[4];
    if (is64) {
        if (n == 4 && (E & 1) == 0) {
            const int4 a = *(const int4*)(ei + 2 * (size_t)e0);
            const int4 b = *(const int4*)(ei + 2 * (size_t)e0 + 4);
            const int4 c = *(const int4*)(ei + 2 * (size_t)(E + e0));
            const int4 f = *(const int4*)(ei + 2 * (size_t)(E + e0) + 4);
            s[0] = a.x; s[1] = a.z; s[2] = b.x; s[3] = b.z;
            d[0] = c.x; d[1] = c.z; d[2] = f.x; d[3] = f.z;
        } else {
            for (int i = 0; i < 4; ++i) {
                s[i] = (i < n) ? ei[2 * (size_t)(e0 + i)] : 0;
                d[i] = (i < n) ? ei[2 * (size_t)(E + e0 + i)] : 0;
            }
        }
    } else {
        if (n == 4 && (E & 3) == 0) {
            const int4 a = *(const int4*)(ei + e0);
            const int4 c = *(const int4*)(ei + E + e0);
            s[0] = a.x; s[1] = a.y; s[2] = a.z; s[3] = a.w;
            d[0] = c.x; d[1] = c.y; d[2] = c.z; d[3] = c.w;
        } else {
            for (int i = 0; i < 4; ++i) {
                s[i] = (i < n) ? ei[e0 + i] : 0;
                d[i] = (i < n) ? ei[E + e0 + i] : 0;
            }
        }
    }
    int p[4];
#pragma unroll
    for (int i = 0; i < 4; ++i) {
        if (i < n) {
            int dd = d[i]; dd = (dd < 0) ? 0 : (dd >= Nn ? Nn - 1 : dd);
            p[i] = atomicAdd(&cursor[dd], 1);
        }
    }
#pragma unroll
    for (int i = 0; i < 4; ++i) {
        if (i < n) {
            int ss = s[i]; ss = (ss < 0) ? 0 : (ss >= Nn ? Nn - 1 : ss);
            srcs[p[i]] = (ushort_t)ss;
        }
    }
}

// ---------------- aggregation: persistent waves, interleaved node striding ----------------
// Old version: one wave per node, static block assignment -> block retires at max of
// 4 Poisson(16) degrees, occupancy 65%. New: 2048 blocks (exactly 8/CU resident),
// each wave strides node += nWaves -> per-CU work 3125 +- 56 edges. 8-deep edge unroll.

__global__ __launch_bounds__(256)
void agg_kernel(const ushort_t* __restrict__ xin, const int* __restrict__ row_ptr,
                const ushort_t* __restrict__ srcs, ushort_t* __restrict__ aggout,
                int Nn, int nWaves) {
    const int lane = threadIdx.x & 63;
    const int wave = (blockIdx.x * blockDim.x + threadIdx.x) >> 6;
    const int off = lane * 4;
    for (int node = wave; node < Nn; node += nWaves) {
        const int beg = row_ptr[node], end = row_ptr[node + 1];
        float a0 = 0.f, a1 = 0.f, a2 = 0.f, a3 = 0.f;
        int e = beg;
        for (; e + 7 < end; e += 8) {
            int s[8];
#pragma unroll
            for (int i = 0; i < 8; ++i) s[i] = srcs[e + i];
            ushort4 v[8];
#pragma unroll
            for (int i = 0; i < 8; ++i)
                v[i] = *(const ushort4*)(xin + (size_t)s[i] * DIM + off);
#pragma unroll
            for (int i = 0; i < 8; ++i) {
                a0 += bf2f(v[i].x); a1 += bf2f(v[i].y); a2 += bf2f(v[i].z); a3 += bf2f(v[i].w);
            }
        }
        for (; e + 3 < end; e += 4) {
            int s0 = srcs[e], s1 = srcs[e + 1], s2 = srcs[e + 2], s3 = srcs[e + 3];
            const ushort4 v0 = *(const ushort4*)(xin + (size_t)s0 * DIM + off);
            const ushort4 v1 = *(const ushort4*)(xin + (size_t)s1 * DIM + off);
            const ushort4 v2 = *(const ushort4*)(xin + (size_t)s2 * DIM + off);
            const ushort4 v3 = *(const ushort4*)(xin + (size_t)s3 * DIM + off);
            a0 += bf2f(v0.x); a1 += bf2f(v0.y); a2 += bf2f(v0.z); a3 += bf2f(v0.w);
            a0 += bf2f(v1.x); a1 += bf2f(v1.y); a2 += bf2f(v1.z); a3 += bf2f(v1.w);
            a0 += bf2f(v2.x); a1 += bf2f(v2.y); a2 += bf2f(v2.z); a3 += bf2f(v2.w);
            a0 += bf2f(v3.x); a1 += bf2f(v3.y); a2 += bf2f(v3.z); a3 += bf2f(v3.w);
        }
        for (; e < end; ++e) {
            int s = srcs[e];
            const ushort4 v = *(const ushort4*)(xin + (size_t)s * DIM + off);
            a0 += bf2f(v.x); a1 += bf2f(v.y); a2 += bf2f(v.z); a3 += bf2f(v.w);
        }
        ushort4 o;
        o.x = f2bf(a0); o.y = f2bf(a1); o.z = f2bf(a2); o.w = f2bf(a3);
        *(ushort4*)(aggout + (size_t)node * DIM + off) = o;
    }
}

// ---------------- fused GEMM: out = elu([agg|root] @ W + bias) — two 32KB K-phases ----------------
// BM=64, BN=256, 4 waves (wave w -> cols [w*64,w*64+64)), 4x4 MFMA 16x16x32 frags.
// LDS halved to 32KB (As[8][64][32]): stage agg half -> compute ks 0..7 -> restage root
// half into SAME buffer -> compute ks 8..15 (acc carries). 3 barriers instead of 1, but
// __launch_bounds__(256,3) -> 3 blocks/CU resident (768 slots ~= 782 blocks, single-shot,
// no 2-round tail) and 12 waves/CU to hide the global B-frag loads.

template <bool OUT_F32>
__global__ __launch_bounds__(256, 3)
void gemm_fused_kernel(const ushort_t* __restrict__ Aagg, const ushort_t* __restrict__ Ax,
                       const ushort_t* __restrict__ Bp, const float* __restrict__ bias,
                       void* __restrict__ outp, int M) {
    __shared__ __align__(16) ushort_t As[8 * 64 * 32];   // 32 KB
    const int t = threadIdx.x;
    const int w = t >> 6, l = t & 63;
    const int bm = blockIdx.x;

    // ---- staging geometry (same m97-verified pattern: LDS dest = base + lane*16B) ----
    const int sub = l >> 2;                 // row-within-16
    const int kq  = l & 3;                  // 16B chunk within 64B tile-row
    const int arow = w * 16 + sub;
    int ga = bm * 64 + arow; if (ga > M - 1) ga = M - 1;
    const ushort_t* aggRow = Aagg + (size_t)ga * DIM + kq * 8;
    const ushort_t* axRow  = Ax   + (size_t)ga * DIM + kq * 8;
    ushort_t* AsW = &As[(w * 16) * 32];     // + lane*16B implicit per tile

    // ---- phase 1: stage agg half (tiles 0..7) ----
#pragma unroll
    for (int ks = 0; ks < 8; ++ks)
        gload_lds16(aggRow + ks * 32, AsW + ks * (64 * 32));
    __syncthreads();

    f32x4 acc[4][4] = {};
    const int mrow = l & 15;
    const int koff = (l >> 4) * 8;
    const ushort_t* BpW = Bp + ((size_t)(w * 4) * 64 + l) * 8;   // nt0 = w*4
    // strides in halves: ks -> 16*64*8 = 8192, nt -> 64*8 = 512

#pragma unroll 4
    for (int ks = 0; ks < 8; ++ks) {
        short8 bf0 = *(const short8*)(BpW + (size_t)ks * 8192 + 0 * 512);
        short8 bf1 = *(const short8*)(BpW + (size_t)ks * 8192 + 1 * 512);
        short8 bf2 = *(const short8*)(BpW + (size_t)ks * 8192 + 2 * 512);
        short8 bf3 = *(const short8*)(BpW + (size_t)ks * 8192 + 3 * 512);
        short8 af[4];
#pragma unroll
        for (int mi = 0; mi < 4; ++mi)
            af[mi] = *(const short8*)&As[(ks * 64 + mrow + mi * 16) * 32 + koff];
#pragma unroll
        for (int mi = 0; mi < 4; ++mi) {
            acc[mi][0] = __builtin_amdgcn_mfma_f32_16x16x32_bf16(af[mi], bf0, acc[mi][0], 0, 0, 0);
            acc[mi][1] = __builtin_amdgcn_mfma_f32_16x16x32_bf16(af[mi], bf1, acc[mi][1], 0, 0, 0);
            acc[mi][2] = __builtin_amdgcn_mfma_f32_16x16x32_bf16(af[mi], bf2, acc[mi][2], 0, 0, 0);
            acc[mi][3] = __builtin_amdgcn_mfma_f32_16x16x32_bf16(af[mi], bf3, acc[mi][3], 0, 0, 0);
        }
    }
    __syncthreads();   // all waves done reading phase-1 A tiles

    // ---- phase 2: restage root half into the same 32KB ----
#pragma unroll
    for (int ks = 0; ks < 8; ++ks)
        gload_lds16(axRow + ks * 32, AsW + ks * (64 * 32));
    __syncthreads();

#pragma unroll 4
    for (int ks = 8; ks < 16; ++ks) {
        short8 bf0 = *(const short8*)(BpW + (size_t)ks * 8192 + 0 * 512);
        short8 bf1 = *(const short8*)(BpW + (size_t)ks * 8192 + 1 * 512);
        short8 bf2 = *(const short8*)(BpW + (size_t)ks * 8192 + 2 * 512);
        short8 bf3 = *(const short8*)(BpW + (size_t)ks * 8192 + 3 * 512);
        short8 af[4];
#pragma unroll
        for (int mi = 0; mi < 4; ++mi)
            af[mi] = *(const short8*)&As[((ks - 8) * 64 + mrow + mi * 16) * 32 + koff];
#pragma unroll
        for (int mi = 0; mi < 4; ++mi) {
            acc[mi][0] = __builtin_amdgcn_mfma_f32_16x16x32_bf16(af[mi], bf0, acc[mi][0], 0, 0, 0);
            acc[mi][1] = __builtin_amdgcn_mfma_f32_16x16x32_bf16(af[mi], bf1, acc[mi][1], 0, 0, 0);
            acc[mi][2] = __builtin_amdgcn_mfma_f32_16x16x32_bf16(af[mi], bf2, acc[mi][2], 0, 0, 0);
            acc[mi][3] = __builtin_amdgcn_mfma_f32_16x16x32_bf16(af[mi], bf3, acc[mi][3], 0, 0, 0);
        }
    }

    // epilogue: bias + ELU; C/D layout col=lane&15, row=(lane>>4)*4+reg
    const int col0 = w * 64 + (l & 15);
    const int rb   = bm * 64 + ((l >> 4) << 2);
    float bv[4];
#pragma unroll
    for (int ni = 0; ni < 4; ++ni) bv[ni] = bias[col0 + ni * 16];
#pragma unroll
    for (int mi = 0; mi < 4; ++mi) {
#pragma unroll
        for (int r = 0; r < 4; ++r) {
            int node = rb + mi * 16 + r;
            if (node < M) {
#pragma unroll
                for (int ni = 0; ni < 4; ++ni) {
                    float v = acc[mi][ni][r] + bv[ni];
                    v = v > 0.f ? v : (__expf(v) - 1.f);
                    if (OUT_F32)
                        ((float*)outp)[(size_t)node * DIM + col0 + ni * 16] = v;
                    else
                        ((ushort_t*)outp)[(size_t)node * DIM + col0 + ni * 16] = f2bf(v);
                }
            }
        }
    }
}

// ---------------- launcher ----------------
// fp32 in / fp32 out per the reference dtypes. Internals in bf16.
// d_out hosts xb and h1 (both dead before layer-3 fp32 overwrite).

extern "C" void kernel_launch(void* const* d_in, const int* in_sizes, int n_in,
                              void* d_out, int out_size, void* d_ws, size_t ws_size,
                              hipStream_t stream) {
    const float* x  = (const float*)d_in[0];
    const int*   ei = (const int*)d_in[1];
    const float* Wrel[3] = { (const float*)d_in[2], (const float*)d_in[5], (const float*)d_in[8] };
    const float* bias[3] = { (const float*)d_in[3], (const float*)d_in[6], (const float*)d_in[9] };
    const float* Wroot[3]= { (const float*)d_in[4], (const float*)d_in[7], (const float*)d_in[10] };

    const int Nn = in_sizes[0] / DIM;      // 50000
    const int E  = in_sizes[1] / 2;        // 800000

    char* ws = (char*)d_ws;
    size_t off = 0;
    auto alloc = [&](size_t bytes) {
        char* p = ws + off;
        off = (off + bytes + 1023) & ~(size_t)1023;
        return p;
    };
    int* flag     = (int*)alloc(4);
    int* deg      = (int*)alloc((size_t)Nn * 4);
    int* row_ptr  = (int*)alloc((size_t)(Nn + 1) * 4);
    int* cursor   = (int*)alloc((size_t)Nn * 4);
    int* partials = (int*)alloc(64 * 4);
    ushort_t* srcs= (ushort_t*)alloc((size_t)E * 2);                // uint16 srcs
    ushort_t* Wt  = (ushort_t*)alloc((size_t)3 * DIM * KDIM * 2);   // 3 layers, frag-tile packed
    ushort_t* aggbuf = (ushort_t*)alloc((size_t)Nn * DIM * 2);
    ushort_t* h2     = (ushort_t*)alloc((size_t)Nn * DIM * 2);
    (void)ws_size; (void)n_in; (void)out_size;

    ushort_t* xb = (ushort_t*)d_out;            // bf16 x copy (d_out lower half)
    ushort_t* h1 = xb + (size_t)Nn * DIM;       // bf16 hidden-1 (d_out upper half)

    // 1) probe + prep (convert | pack | hist) + scan + fill
    const int n4 = Nn * DIM / 4;
    const int cb = (n4 + 255) / 256;                     // 12500
    const int pb = (3 * DIM * KDIM + 255) / 256;         // 1536
    const int eq = (E + 3) / 4;                          // edge quads
    const int hb = (eq + 255) / 256;                     // 782 (hist + fill blocks)
    const int nb = (Nn + 1023) / 1024;                   // 49 scan blocks

    detect_kernel<<<1, 256, 0, stream>>>(ei, flag);
    hipMemsetAsync(deg, 0, (size_t)Nn * 4, stream);
    prep_kernel<<<cb + pb + hb, 256, 0, stream>>>(
        x, xb, n4, cb,
        Wrel[0], Wroot[0], Wrel[1], Wroot[1], Wrel[2], Wroot[2], Wt, pb,
        ei, flag, deg, E, Nn);
    scan1_kernel<<<nb, 256, 0, stream>>>(deg, partials, Nn);
    scan3_kernel<<<nb, 256, 0, stream>>>(deg, partials, row_ptr, cursor, Nn, E);
    fill_kernel<<<hb, 256, 0, stream>>>(ei, flag, cursor, srcs, E, Nn);

    // 2) three GraphConv layers
    const int aggBlocks = 2048;                           // 8 blocks/CU resident, persistent
    const int nWaves    = aggBlocks * 4;
    const int gBlocks   = (Nn + 63) / 64;                 // 782

    agg_kernel<<<aggBlocks, 256, 0, stream>>>(xb, row_ptr, srcs, aggbuf, Nn, nWaves);
    gemm_fused_kernel<false><<<gBlocks, 256, 0, stream>>>(aggbuf, xb, Wt, bias[0], h1, Nn);

    agg_kernel<<<aggBlocks, 256, 0, stream>>>(h1, row_ptr, srcs, aggbuf, Nn, nWaves);
    gemm_fused_kernel<false><<<gBlocks, 256, 0, stream>>>(aggbuf, h1, Wt + DIM * KDIM, bias[1], h2, Nn);

    agg_kernel<<<aggBlocks, 256, 0, stream>>>(h2, row_ptr, srcs, aggbuf, Nn, nWaves);
    gemm_fused_kernel<true><<<gBlocks, 256, 0, stream>>>(aggbuf, h2, Wt + 2 * DIM * KDIM, bias[2], d_out, Nn);
}

// Round 2
// 444.038 us; speedup vs baseline: 1.0440x; 1.0140x over previous
//
#include <hip/hip_runtime.h>
#include <hip/hip_bf16.h>

// Problem constants (shapes fixed by the reference)
#define DIM 256          // feature dim (D == H == 256)
#define KDIM 512         // fused K = D(agg) + D(root)

typedef unsigned short ushort_t;
typedef __attribute__((ext_vector_type(8))) short short8;   // 8 x bf16 (4 VGPRs) MFMA A/B frag
typedef __attribute__((ext_vector_type(4))) float f32x4;    // MFMA C/D frag

__device__ __forceinline__ float bf2f(ushort_t u) {
    union { unsigned int i; float f; } c; c.i = ((unsigned int)u) << 16; return c.f;
}
__device__ __forceinline__ ushort_t f2bf(float f) {
    unsigned int x = __float_as_uint(f);
    unsigned int r = (x + 0x7fffu + ((x >> 16) & 1u)) >> 16;
    return (ushort_t)r;
}

// async global->LDS, 16B/lane; LDS dest = wave-uniform base + lane*16
__device__ __forceinline__ void gload_lds16(const ushort_t* g, ushort_t* l) {
    __builtin_amdgcn_global_load_lds(
        (const __attribute__((address_space(1))) unsigned int*)g,
        (__attribute__((address_space(3))) unsigned int*)l, 16, 0, 0);
}

// ---------------- edge_index dtype probe (ONCE; flag read is scalar thereafter) ----------------
__global__ void detect_kernel(const int* __restrict__ ei, int* __restrict__ flag) {
    __shared__ int any;
    if (threadIdx.x == 0) any = 0;
    __syncthreads();
    if (ei[2 * threadIdx.x + 1] != 0) atomicOr(&any, 1);
    __syncthreads();
    if (threadIdx.x == 0) *flag = (any == 0) ? 1 : 0;   // 1 => int64 layout
}

// ---------------- prep: convert x->bf16 | pack 3 weight sets (frag tiles) | histogram ----------------
// B pack layout per layer: Bp[ks][nt][lane][h]  (16*16*64*8 halves = 256 KB)
//   n = nt*16 + (lane&15),  k = ks*32 + (lane>>4)*8 + h
// => wave B-frag (ks, nt) is ONE contiguous 1KB block, coalesced global->VGPR.
// Histogram branch: 4 edges/thread, coalesced int4 loads, 4 independent atomics.

__global__ __launch_bounds__(256)
void prep_kernel(const float* __restrict__ x, ushort_t* __restrict__ xb, int n4, int cb,
                 const float* __restrict__ W0r, const float* __restrict__ W0o,
                 const float* __restrict__ W1r, const float* __restrict__ W1o,
                 const float* __restrict__ W2r, const float* __restrict__ W2o,
                 ushort_t* __restrict__ Wt, int pb,
                 const int* __restrict__ ei, const int* __restrict__ flag,
                 int* __restrict__ deg, int E, int Nn) {
    int bid = blockIdx.x;
    int t = threadIdx.x;
    if (bid < cb) {
        int i = bid * 256 + t;
        if (i < n4) {
            const float4 v = *(const float4*)(x + (size_t)i * 4);
            ushort4 o;
            o.x = f2bf(v.x); o.y = f2bf(v.y); o.z = f2bf(v.z); o.w = f2bf(v.w);
            *(ushort4*)(xb + (size_t)i * 4) = o;
        }
    } else if (bid < cb + pb) {
        int id = (bid - cb) * 256 + t;            // over 3*131072
        int layer = id >> 17;
        int rem = id & 131071;
        int ks   = rem >> 13;                     // 8192 per ks
        int nt   = (rem >> 9) & 15;
        int lane = (rem >> 3) & 63;
        int h    = rem & 7;
        int n = nt * 16 + (lane & 15);
        int k = ks * 32 + ((lane >> 4) << 3) + h;
        const float* Wr = (layer == 0) ? W0r : (layer == 1) ? W1r : W2r;
        const float* Wo = (layer == 0) ? W0o : (layer == 1) ? W1o : W2o;
        float v = (k < DIM) ? Wr[k * DIM + n] : Wo[(k - DIM) * DIM + n];
        Wt[id] = f2bf(v);
    } else {
        int q = (bid - cb - pb) * 256 + t;        // quad index: 4 edges each
        int e0 = q * 4;
        if (e0 < E) {
            const int is64 = *flag;               // wave-uniform scalar load
            const int n = (E - e0 < 4) ? (E - e0) : 4;
            int d[4];
            if (is64) {
                if (n == 4 && (E & 1) == 0) {
                    const int4 c = *(const int4*)(ei + 2 * (size_t)(E + e0));
                    const int4 f = *(const int4*)(ei + 2 * (size_t)(E + e0) + 4);
                    d[0] = c.x; d[1] = c.z; d[2] = f.x; d[3] = f.z;
                } else {
                    for (int i = 0; i < 4; ++i) d[i] = (i < n) ? ei[2 * (size_t)(E + e0 + i)] : 0;
                }
            } else {
                if (n == 4 && (E & 3) == 0) {
                    const int4 c = *(const int4*)(ei + E + e0);
                    d[0] = c.x; d[1] = c.y; d[2] = c.z; d[3] = c.w;
                } else {
                    for (int i = 0; i < 4; ++i) d[i] = (i < n) ? ei[E + e0 + i] : 0;
                }
            }
#pragma unroll
            for (int i = 0; i < 4; ++i) {
                if (i < n) {
                    int dd = d[i]; dd = (dd < 0) ? 0 : (dd >= Nn ? Nn - 1 : dd);
                    atomicAdd(&deg[dd], 1);
                }
            }
        }
    }
}

// ---------------- scan: deg -> row_ptr/cursor (2 kernels) ----------------

__global__ __launch_bounds__(256)
void scan1_kernel(const int* __restrict__ deg, int* __restrict__ partials, int Nn) {
    __shared__ int red[256];
    int t = threadIdx.x;
    int base = blockIdx.x * 1024 + t * 4;
    int s = 0;
    if (base + 3 < Nn) {
        const int4 v = *(const int4*)(deg + base);
        s = v.x + v.y + v.z + v.w;
    } else {
        for (int i = 0; i < 4; ++i) if (base + i < Nn) s += deg[base + i];
    }
    red[t] = s;
    __syncthreads();
    for (int off = 128; off > 0; off >>= 1) {
        if (t < off) red[t] += red[t + off];
        __syncthreads();
    }
    if (t == 0) partials[blockIdx.x] = red[0];
}

__global__ __launch_bounds__(256)
void scan3_kernel(const int* __restrict__ deg, const int* __restrict__ partials,
                  int* __restrict__ row_ptr, int* __restrict__ cursor, int Nn, int E) {
    __shared__ int sdata[256];
    int t = threadIdx.x;
    int pref = 0;
    for (int i = 0; i < blockIdx.x; ++i) pref += partials[i];   // <=49 L2-hot loads
    int base = blockIdx.x * 1024 + t * 4;
    int d0 = 0, d1 = 0, d2 = 0, d3 = 0;
    if (base + 3 < Nn) {
        const int4 v = *(const int4*)(deg + base);
        d0 = v.x; d1 = v.y; d2 = v.z; d3 = v.w;
    } else {
        if (base + 0 < Nn) d0 = deg[base + 0];
        if (base + 1 < Nn) d1 = deg[base + 1];
        if (base + 2 < Nn) d2 = deg[base + 2];
        if (base + 3 < Nn) d3 = deg[base + 3];
    }
    int tsum = d0 + d1 + d2 + d3;
    sdata[t] = tsum;
    __syncthreads();
    for (int off = 1; off < 256; off <<= 1) {
        int u = (t >= off) ? sdata[t - off] : 0;
        __syncthreads();
        sdata[t] += u;
        __syncthreads();
    }
    int p0 = sdata[t] - tsum + pref;
    int p1 = p0 + d0, p2 = p1 + d1, p3 = p2 + d2;
    if (base + 3 < Nn) {
        *(int4*)(row_ptr + base) = make_int4(p0, p1, p2, p3);
        *(int4*)(cursor  + base) = make_int4(p0, p1, p2, p3);
    } else {
        if (base + 0 < Nn) { row_ptr[base + 0] = p0; cursor[base + 0] = p0; }
        if (base + 1 < Nn) { row_ptr[base + 1] = p1; cursor[base + 1] = p1; }
        if (base + 2 < Nn) { row_ptr[base + 2] = p2; cursor[base + 2] = p2; }
        if (base + 3 < Nn) { row_ptr[base + 3] = p3; cursor[base + 3] = p3; }
    }
    if (blockIdx.x == 0 && t == 0) row_ptr[Nn] = E;
}

// ---------------- fill: 4 edges/thread, int4-coalesced ei loads, uint16 srcs ----------------

__global__ __launch_bounds__(256)
void fill_kernel(const int* __restrict__ ei, const int* __restrict__ flag,
                 int* __restrict__ cursor, ushort_t* __restrict__ srcs, int E, int Nn) {
    int q = blockIdx.x * blockDim.x + threadIdx.x;
    int e0 = q * 4;
    if (e0 >= E) return;
    const int is64 = *flag;                       // wave-uniform scalar load
    const int n = (E - e0 < 4) ? (E - e0) : 4;
    int s[4], d[4];
    if (is64) {
        if (n == 4 && (E & 1) == 0) {
            const int4 a = *(const int4*)(ei + 2 * (size_t)e0);
            const int4 b = *(const int4*)(ei + 2 * (size_t)e0 + 4);
            const int4 c = *(const int4*)(ei + 2 * (size_t)(E + e0));
            const int4 f = *(const int4*)(ei + 2 * (size_t)(E + e0) + 4);
            s[0] = a.x; s[1] = a.z; s[2] = b.x; s[3] = b.z;
            d[0] = c.x; d[1] = c.z; d[2] = f.x; d[3] = f.z;
        } else {
            for (int i = 0; i < 4; ++i) {
                s[i] = (i < n) ? ei[2 * (size_t)(e0 + i)] : 0;
                d[i] = (i < n) ? ei[2 * (size_t)(E + e0 + i)] : 0;
            }
        }
    } else {
        if (n == 4 && (E & 3) == 0) {
            const int4 a = *(const int4*)(ei + e0);
            const int4 c = *(const int4*)(ei + E + e0);
            s[0] = a.x; s[1] = a.y; s[2] = a.z; s[3] = a.w;
            d[0] = c.x; d[1] = c.y; d[2] = c.z; d[3] = c.w;
        } else {
            for (int i = 0; i < 4; ++i) {
                s[i] = (i < n) ? ei[e0 + i] : 0;
                d[i] = (i < n) ? ei[E + e0 + i] : 0;
            }
        }
    }
    int p[4];
#pragma unroll
    for (int i = 0; i < 4; ++i) {
        if (i < n) {
            int dd = d[i]; dd = (dd < 0) ? 0 : (dd >= Nn ? Nn - 1 : dd);
            p[i] = atomicAdd(&cursor[dd], 1);
        }
    }
#pragma unroll
    for (int i = 0; i < 4; ++i) {
        if (i < n) {
            int ss = s[i]; ss = (ss < 0) ? 0 : (ss >= Nn ? Nn - 1 : ss);
            srcs[p[i]] = (ushort_t)ss;
        }
    }
}

// ---------------- aggregation: half-wave split, 16B/lane gathers ----------------
// R1 post-mortem: persistent grid did NOT help (58.6us, VALUBusy 29%) -> agg is
// latency-chain-bound per wave, not occupancy-bound. Fix the chain itself:
//   - lane covers 8 bf16 (16B) -> 32 lanes span the 256-dim row
//   - ONE global_load_dwordx4 wave instruction gathers TWO edges (lanes 0-31 =
//     edge e, lanes 32-63 = edge e+1, same node, stride-2 interleave)
//   - gather instruction count halves (800k->400k), per-node serial edge chain
//     halves, bytes-in-flight per wave doubles
//   - final combine: 8x __shfl_xor(...,32); half 0 stores the 512B row.

__global__ __launch_bounds__(256)
void agg_kernel(const ushort_t* __restrict__ xin, const int* __restrict__ row_ptr,
                const ushort_t* __restrict__ srcs, ushort_t* __restrict__ aggout,
                int Nn, int nWaves) {
    const int lane = threadIdx.x & 63;
    const int half = lane >> 5;              // 0 or 1: which edge of the pair
    const int hl   = lane & 31;              // lane-within-half: dim chunk
    const int wave = (blockIdx.x * blockDim.x + threadIdx.x) >> 6;
    const size_t off = (size_t)hl * 8;       // 8 bf16 per lane
    for (int node = wave; node < Nn; node += nWaves) {
        const int beg = row_ptr[node], end = row_ptr[node + 1];
        const int deg = end - beg;
        float a[8] = {};
        // half h handles edges h, h+2, h+4, ... (stride-2 interleave)
        int e = half;
        for (; e + 6 < deg; e += 8) {        // 4 edges per half per iter = 8/wave
            const int s0 = srcs[beg + e];
            const int s1 = srcs[beg + e + 2];
            const int s2 = srcs[beg + e + 4];
            const int s3 = srcs[beg + e + 6];
            const short8 v0 = *(const short8*)(xin + (size_t)s0 * DIM + off);
            const short8 v1 = *(const short8*)(xin + (size_t)s1 * DIM + off);
            const short8 v2 = *(const short8*)(xin + (size_t)s2 * DIM + off);
            const short8 v3 = *(const short8*)(xin + (size_t)s3 * DIM + off);
#pragma unroll
            for (int i = 0; i < 8; ++i) {
                a[i] += bf2f((ushort_t)v0[i]);
                a[i] += bf2f((ushort_t)v1[i]);
                a[i] += bf2f((ushort_t)v2[i]);
                a[i] += bf2f((ushort_t)v3[i]);
            }
        }
        for (; e < deg; e += 2) {
            const int s = srcs[beg + e];
            const short8 v = *(const short8*)(xin + (size_t)s * DIM + off);
#pragma unroll
            for (int i = 0; i < 8; ++i) a[i] += bf2f((ushort_t)v[i]);
        }
        // combine the two halves (each lane pairs with lane^32, same dim chunk)
#pragma unroll
        for (int i = 0; i < 8; ++i) a[i] += __shfl_xor(a[i], 32, 64);
        if (half == 0) {
            short8 o;
#pragma unroll
            for (int i = 0; i < 8; ++i) o[i] = (short)f2bf(a[i]);
            *(short8*)(aggout + (size_t)node * DIM + off) = o;
        }
    }
}

// ---------------- fused GEMM: out = elu([agg|root] @ W + bias) — two 32KB K-phases ----------------
// BM=64, BN=256, 4 waves (wave w -> cols [w*64,w*64+64)), 4x4 MFMA 16x16x32 frags.
// LDS 32KB (As[8][64][32]): stage agg half -> compute ks 0..7 -> restage root
// half into SAME buffer -> compute ks 8..15 (acc carries). __launch_bounds__(256,3)
// -> 3 blocks/CU resident (768 slots ~= 782 blocks) and 12 waves/CU.

template <bool OUT_F32>
__global__ __launch_bounds__(256, 3)
void gemm_fused_kernel(const ushort_t* __restrict__ Aagg, const ushort_t* __restrict__ Ax,
                       const ushort_t* __restrict__ Bp, const float* __restrict__ bias,
                       void* __restrict__ outp, int M) {
    __shared__ __align__(16) ushort_t As[8 * 64 * 32];   // 32 KB
    const int t = threadIdx.x;
    const int w = t >> 6, l = t & 63;
    const int bm = blockIdx.x;

    // ---- staging geometry (m97-verified pattern: LDS dest = base + lane*16B) ----
    const int sub = l >> 2;                 // row-within-16
    const int kq  = l & 3;                  // 16B chunk within 64B tile-row
    const int arow = w * 16 + sub;
    int ga = bm * 64 + arow; if (ga > M - 1) ga = M - 1;
    const ushort_t* aggRow = Aagg + (size_t)ga * DIM + kq * 8;
    const ushort_t* axRow  = Ax   + (size_t)ga * DIM + kq * 8;
    ushort_t* AsW = &As[(w * 16) * 32];     // + lane*16B implicit per tile

    // ---- phase 1: stage agg half (tiles 0..7) ----
#pragma unroll
    for (int ks = 0; ks < 8; ++ks)
        gload_lds16(aggRow + ks * 32, AsW + ks * (64 * 32));
    __syncthreads();

    f32x4 acc[4][4] = {};
    const int mrow = l & 15;
    const int koff = (l >> 4) * 8;
    const ushort_t* BpW = Bp + ((size_t)(w * 4) * 64 + l) * 8;   // nt0 = w*4
    // strides in halves: ks -> 16*64*8 = 8192, nt -> 64*8 = 512

#pragma unroll 4
    for (int ks = 0; ks < 8; ++ks) {
        short8 bf0 = *(const short8*)(BpW + (size_t)ks * 8192 + 0 * 512);
        short8 bf1 = *(const short8*)(BpW + (size_t)ks * 8192 + 1 * 512);
        short8 bf2 = *(const short8*)(BpW + (size_t)ks * 8192 + 2 * 512);
        short8 bf3 = *(const short8*)(BpW + (size_t)ks * 8192 + 3 * 512);
        short8 af[4];
#pragma unroll
        for (int mi = 0; mi < 4; ++mi)
            af[mi] = *(const short8*)&As[(ks * 64 + mrow + mi * 16) * 32 + koff];
#pragma unroll
        for (int mi = 0; mi < 4; ++mi) {
            acc[mi][0] = __builtin_amdgcn_mfma_f32_16x16x32_bf16(af[mi], bf0, acc[mi][0], 0, 0, 0);
            acc[mi][1] = __builtin_amdgcn_mfma_f32_16x16x32_bf16(af[mi], bf1, acc[mi][1], 0, 0, 0);
            acc[mi][2] = __builtin_amdgcn_mfma_f32_16x16x32_bf16(af[mi], bf2, acc[mi][2], 0, 0, 0);
            acc[mi][3] = __builtin_amdgcn_mfma_f32_16x16x32_bf16(af[mi], bf3, acc[mi][3], 0, 0, 0);
        }
    }
    __syncthreads();   // all waves done reading phase-1 A tiles

    // ---- phase 2: restage root half into the same 32KB ----
#pragma unroll
    for (int ks = 0; ks < 8; ++ks)
        gload_lds16(axRow + ks * 32, AsW + ks * (64 * 32));
    __syncthreads();

#pragma unroll 4
    for (int ks = 8; ks < 16; ++ks) {
        short8 bf0 = *(const short8*)(BpW + (size_t)ks * 8192 + 0 * 512);
        short8 bf1 = *(const short8*)(BpW + (size_t)ks * 8192 + 1 * 512);
        short8 bf2 = *(const short8*)(BpW + (size_t)ks * 8192 + 2 * 512);
        short8 bf3 = *(const short8*)(BpW + (size_t)ks * 8192 + 3 * 512);
        short8 af[4];
#pragma unroll
        for (int mi = 0; mi < 4; ++mi)
            af[mi] = *(const short8*)&As[((ks - 8) * 64 + mrow + mi * 16) * 32 + koff];
#pragma unroll
        for (int mi = 0; mi < 4; ++mi) {
            acc[mi][0] = __builtin_amdgcn_mfma_f32_16x16x32_bf16(af[mi], bf0, acc[mi][0], 0, 0, 0);
            acc[mi][1] = __builtin_amdgcn_mfma_f32_16x16x32_bf16(af[mi], bf1, acc[mi][1], 0, 0, 0);
            acc[mi][2] = __builtin_amdgcn_mfma_f32_16x16x32_bf16(af[mi], bf2, acc[mi][2], 0, 0, 0);
            acc[mi][3] = __builtin_amdgcn_mfma_f32_16x16x32_bf16(af[mi], bf3, acc[mi][3], 0, 0, 0);
        }
    }

    // epilogue: bias + ELU; C/D layout col=lane&15, row=(lane>>4)*4+reg
    const int col0 = w * 64 + (l & 15);
    const int rb   = bm * 64 + ((l >> 4) << 2);
    float bv[4];
#pragma unroll
    for (int ni = 0; ni < 4; ++ni) bv[ni] = bias[col0 + ni * 16];
#pragma unroll
    for (int mi = 0; mi < 4; ++mi) {
#pragma unroll
        for (int r = 0; r < 4; ++r) {
            int node = rb + mi * 16 + r;
            if (node < M) {
#pragma unroll
                for (int ni = 0; ni < 4; ++ni) {
                    float v = acc[mi][ni][r] + bv[ni];
                    v = v > 0.f ? v : (__expf(v) - 1.f);
                    if (OUT_F32)
                        ((float*)outp)[(size_t)node * DIM + col0 + ni * 16] = v;
                    else
                        ((ushort_t*)outp)[(size_t)node * DIM + col0 + ni * 16] = f2bf(v);
                }
            }
        }
    }
}

// ---------------- launcher ----------------
// fp32 in / fp32 out per the reference dtypes. Internals in bf16.
// d_out hosts xb and h1 (both dead before layer-3 fp32 overwrite).

extern "C" void kernel_launch(void* const* d_in, const int* in_sizes, int n_in,
                              void* d_out, int out_size, void* d_ws, size_t ws_size,
                              hipStream_t stream) {
    const float* x  = (const float*)d_in[0];
    const int*   ei = (const int*)d_in[1];
    const float* Wrel[3] = { (const float*)d_in[2], (const float*)d_in[5], (const float*)d_in[8] };
    const float* bias[3] = { (const float*)d_in[3], (const float*)d_in[6], (const float*)d_in[9] };
    const float* Wroot[3]= { (const float*)d_in[4], (const float*)d_in[7], (const float*)d_in[10] };

    const int Nn = in_sizes[0] / DIM;      // 50000
    const int E  = in_sizes[1] / 2;        // 800000

    char* ws = (char*)d_ws;
    size_t off = 0;
    auto alloc = [&](size_t bytes) {
        char* p = ws + off;
        off = (off + bytes + 1023) & ~(size_t)1023;
        return p;
    };
    int* flag     = (int*)alloc(4);
    int* deg      = (int*)alloc((size_t)Nn * 4);
    int* row_ptr  = (int*)alloc((size_t)(Nn + 1) * 4);
    int* cursor   = (int*)alloc((size_t)Nn * 4);
    int* partials = (int*)alloc(64 * 4);
    ushort_t* srcs= (ushort_t*)alloc((size_t)E * 2);                // uint16 srcs
    ushort_t* Wt  = (ushort_t*)alloc((size_t)3 * DIM * KDIM * 2);   // 3 layers, frag-tile packed
    ushort_t* aggbuf = (ushort_t*)alloc((size_t)Nn * DIM * 2);
    ushort_t* h2     = (ushort_t*)alloc((size_t)Nn * DIM * 2);
    (void)ws_size; (void)n_in; (void)out_size;

    ushort_t* xb = (ushort_t*)d_out;            // bf16 x copy (d_out lower half)
    ushort_t* h1 = xb + (size_t)Nn * DIM;       // bf16 hidden-1 (d_out upper half)

    // 1) probe + prep (convert | pack | hist) + scan + fill
    const int n4 = Nn * DIM / 4;
    const int cb = (n4 + 255) / 256;                     // 12500
    const int pb = (3 * DIM * KDIM + 255) / 256;         // 1536
    const int eq = (E + 3) / 4;                          // edge quads
    const int hb = (eq + 255) / 256;                     // 782 (hist + fill blocks)
    const int nb = (Nn + 1023) / 1024;                   // 49 scan blocks

    detect_kernel<<<1, 256, 0, stream>>>(ei, flag);
    hipMemsetAsync(deg, 0, (size_t)Nn * 4, stream);
    prep_kernel<<<cb + pb + hb, 256, 0, stream>>>(
        x, xb, n4, cb,
        Wrel[0], Wroot[0], Wrel[1], Wroot[1], Wrel[2], Wroot[2], Wt, pb,
        ei, flag, deg, E, Nn);
    scan1_kernel<<<nb, 256, 0, stream>>>(deg, partials, Nn);
    scan3_kernel<<<nb, 256, 0, stream>>>(deg, partials, row_ptr, cursor, Nn, E);
    fill_kernel<<<hb, 256, 0, stream>>>(ei, flag, cursor, srcs, E, Nn);

    // 2) three GraphConv layers
    const int aggBlocks = 2048;                           // 8 blocks/CU resident, persistent
    const int nWaves    = aggBlocks * 4;
    const int gBlocks   = (Nn + 63) / 64;                 // 782

    agg_kernel<<<aggBlocks, 256, 0, stream>>>(xb, row_ptr, srcs, aggbuf, Nn, nWaves);
    gemm_fused_kernel<false><<<gBlocks, 256, 0, stream>>>(aggbuf, xb, Wt, bias[0], h1, Nn);

    agg_kernel<<<aggBlocks, 256, 0, stream>>>(h1, row_ptr, srcs, aggbuf, Nn, nWaves);
    gemm_fused_kernel<false><<<gBlocks, 256, 0, stream>>>(aggbuf, h1, Wt + DIM * KDIM, bias[1], h2, Nn);

    agg_kernel<<<aggBlocks, 256, 0, stream>>>(h2, row_ptr, srcs, aggbuf, Nn, nWaves);
    gemm_fused_kernel<true><<<gBlocks, 256, 0, stream>>>(aggbuf, h2, Wt + 2 * DIM * KDIM, bias[2], d_out, Nn);
}

// Round 3
// 430.472 us; speedup vs baseline: 1.0769x; 1.0315x over previous
//
#include <hip/hip_runtime.h>
#include <hip/hip_bf16.h>

// Problem constants (shapes fixed by the reference)
#define DIM 256          // feature dim (D == H == 256)
#define KDIM 512         // fused K = D(agg) + D(root)

typedef unsigned short ushort_t;
typedef __attribute__((ext_vector_type(8))) short short8;   // 8 x bf16 (4 VGPRs) MFMA A/B frag
typedef __attribute__((ext_vector_type(4))) float f32x4;    // MFMA C/D frag

__device__ __forceinline__ float bf2f(ushort_t u) {
    union { unsigned int i; float f; } c; c.i = ((unsigned int)u) << 16; return c.f;
}
__device__ __forceinline__ ushort_t f2bf(float f) {
    unsigned int x = __float_as_uint(f);
    unsigned int r = (x + 0x7fffu + ((x >> 16) & 1u)) >> 16;
    return (ushort_t)r;
}

// async global->LDS, 16B/lane; LDS dest = wave-uniform base + lane*16
__device__ __forceinline__ void gload_lds16(const ushort_t* g, ushort_t* l) {
    __builtin_amdgcn_global_load_lds(
        (const __attribute__((address_space(1))) unsigned int*)g,
        (__attribute__((address_space(3))) unsigned int*)l, 16, 0, 0);
}

// ---------------- edge_index dtype probe (ONCE; flag read is scalar thereafter) ----------------
__global__ void detect_kernel(const int* __restrict__ ei, int* __restrict__ flag) {
    __shared__ int any;
    if (threadIdx.x == 0) any = 0;
    __syncthreads();
    if (ei[2 * threadIdx.x + 1] != 0) atomicOr(&any, 1);
    __syncthreads();
    if (threadIdx.x == 0) *flag = (any == 0) ? 1 : 0;   // 1 => int64 layout
}

// ---------------- prep: convert x->bf16 | pack 3 weight sets (frag tiles) | histogram ----------------
// B pack layout per layer: Bp[ks][nt][lane][h]  (16*16*64*8 halves = 256 KB)
//   n = nt*16 + (lane&15),  k = ks*32 + (lane>>4)*8 + h
// => wave B-frag (ks, nt) is ONE contiguous 1KB block, coalesced global->VGPR.
// Histogram branch: 4 edges/thread, coalesced int4 loads, 4 independent atomics.

__global__ __launch_bounds__(256)
void prep_kernel(const float* __restrict__ x, ushort_t* __restrict__ xb, int n4, int cb,
                 const float* __restrict__ W0r, const float* __restrict__ W0o,
                 const float* __restrict__ W1r, const float* __restrict__ W1o,
                 const float* __restrict__ W2r, const float* __restrict__ W2o,
                 ushort_t* __restrict__ Wt, int pb,
                 const int* __restrict__ ei, const int* __restrict__ flag,
                 int* __restrict__ deg, int E, int Nn) {
    int bid = blockIdx.x;
    int t = threadIdx.x;
    if (bid < cb) {
        int i = bid * 256 + t;
        if (i < n4) {
            const float4 v = *(const float4*)(x + (size_t)i * 4);
            ushort4 o;
            o.x = f2bf(v.x); o.y = f2bf(v.y); o.z = f2bf(v.z); o.w = f2bf(v.w);
            *(ushort4*)(xb + (size_t)i * 4) = o;
        }
    } else if (bid < cb + pb) {
        int id = (bid - cb) * 256 + t;            // over 3*131072
        int layer = id >> 17;
        int rem = id & 131071;
        int ks   = rem >> 13;                     // 8192 per ks
        int nt   = (rem >> 9) & 15;
        int lane = (rem >> 3) & 63;
        int h    = rem & 7;
        int n = nt * 16 + (lane & 15);
        int k = ks * 32 + ((lane >> 4) << 3) + h;
        const float* Wr = (layer == 0) ? W0r : (layer == 1) ? W1r : W2r;
        const float* Wo = (layer == 0) ? W0o : (layer == 1) ? W1o : W2o;
        float v = (k < DIM) ? Wr[k * DIM + n] : Wo[(k - DIM) * DIM + n];
        Wt[id] = f2bf(v);
    } else {
        int q = (bid - cb - pb) * 256 + t;        // quad index: 4 edges each
        int e0 = q * 4;
        if (e0 < E) {
            const int is64 = *flag;               // wave-uniform scalar load
            const int n = (E - e0 < 4) ? (E - e0) : 4;
            int d[4];
            if (is64) {
                if (n == 4 && (E & 1) == 0) {
                    const int4 c = *(const int4*)(ei + 2 * (size_t)(E + e0));
                    const int4 f = *(const int4*)(ei + 2 * (size_t)(E + e0) + 4);
                    d[0] = c.x; d[1] = c.z; d[2] = f.x; d[3] = f.z;
                } else {
                    for (int i = 0; i < 4; ++i) d[i] = (i < n) ? ei[2 * (size_t)(E + e0 + i)] : 0;
                }
            } else {
                if (n == 4 && (E & 3) == 0) {
                    const int4 c = *(const int4*)(ei + E + e0);
                    d[0] = c.x; d[1] = c.y; d[2] = c.z; d[3] = c.w;
                } else {
                    for (int i = 0; i < 4; ++i) d[i] = (i < n) ? ei[E + e0 + i] : 0;
                }
            }
#pragma unroll
            for (int i = 0; i < 4; ++i) {
                if (i < n) {
                    int dd = d[i]; dd = (dd < 0) ? 0 : (dd >= Nn ? Nn - 1 : dd);
                    atomicAdd(&deg[dd], 1);
                }
            }
        }
    }
}

// ---------------- scan: deg -> row_ptr/cursor (2 kernels) ----------------

__global__ __launch_bounds__(256)
void scan1_kernel(const int* __restrict__ deg, int* __restrict__ partials, int Nn) {
    __shared__ int red[256];
    int t = threadIdx.x;
    int base = blockIdx.x * 1024 + t * 4;
    int s = 0;
    if (base + 3 < Nn) {
        const int4 v = *(const int4*)(deg + base);
        s = v.x + v.y + v.z + v.w;
    } else {
        for (int i = 0; i < 4; ++i) if (base + i < Nn) s += deg[base + i];
    }
    red[t] = s;
    __syncthreads();
    for (int off = 128; off > 0; off >>= 1) {
        if (t < off) red[t] += red[t + off];
        __syncthreads();
    }
    if (t == 0) partials[blockIdx.x] = red[0];
}

__global__ __launch_bounds__(256)
void scan3_kernel(const int* __restrict__ deg, const int* __restrict__ partials,
                  int* __restrict__ row_ptr, int* __restrict__ cursor, int Nn, int E) {
    __shared__ int sdata[256];
    int t = threadIdx.x;
    int pref = 0;
    for (int i = 0; i < blockIdx.x; ++i) pref += partials[i];   // <=49 L2-hot loads
    int base = blockIdx.x * 1024 + t * 4;
    int d0 = 0, d1 = 0, d2 = 0, d3 = 0;
    if (base + 3 < Nn) {
        const int4 v = *(const int4*)(deg + base);
        d0 = v.x; d1 = v.y; d2 = v.z; d3 = v.w;
    } else {
        if (base + 0 < Nn) d0 = deg[base + 0];
        if (base + 1 < Nn) d1 = deg[base + 1];
        if (base + 2 < Nn) d2 = deg[base + 2];
        if (base + 3 < Nn) d3 = deg[base + 3];
    }
    int tsum = d0 + d1 + d2 + d3;
    sdata[t] = tsum;
    __syncthreads();
    for (int off = 1; off < 256; off <<= 1) {
        int u = (t >= off) ? sdata[t - off] : 0;
        __syncthreads();
        sdata[t] += u;
        __syncthreads();
    }
    int p0 = sdata[t] - tsum + pref;
    int p1 = p0 + d0, p2 = p1 + d1, p3 = p2 + d2;
    if (base + 3 < Nn) {
        *(int4*)(row_ptr + base) = make_int4(p0, p1, p2, p3);
        *(int4*)(cursor  + base) = make_int4(p0, p1, p2, p3);
    } else {
        if (base + 0 < Nn) { row_ptr[base + 0] = p0; cursor[base + 0] = p0; }
        if (base + 1 < Nn) { row_ptr[base + 1] = p1; cursor[base + 1] = p1; }
        if (base + 2 < Nn) { row_ptr[base + 2] = p2; cursor[base + 2] = p2; }
        if (base + 3 < Nn) { row_ptr[base + 3] = p3; cursor[base + 3] = p3; }
    }
    if (blockIdx.x == 0 && t == 0) row_ptr[Nn] = E;
}

// ---------------- fill: 4 edges/thread, int4-coalesced ei loads, uint16 srcs ----------------

__global__ __launch_bounds__(256)
void fill_kernel(const int* __restrict__ ei, const int* __restrict__ flag,
                 int* __restrict__ cursor, ushort_t* __restrict__ srcs, int E, int Nn) {
    int q = blockIdx.x * blockDim.x + threadIdx.x;
    int e0 = q * 4;
    if (e0 >= E) return;
    const int is64 = *flag;                       // wave-uniform scalar load
    const int n = (E - e0 < 4) ? (E - e0) : 4;
    int s[4], d[4];
    if (is64) {
        if (n == 4 && (E & 1) == 0) {
            const int4 a = *(const int4*)(ei + 2 * (size_t)e0);
            const int4 b = *(const int4*)(ei + 2 * (size_t)e0 + 4);
            const int4 c = *(const int4*)(ei + 2 * (size_t)(E + e0));
            const int4 f = *(const int4*)(ei + 2 * (size_t)(E + e0) + 4);
            s[0] = a.x; s[1] = a.z; s[2] = b.x; s[3] = b.z;
            d[0] = c.x; d[1] = c.z; d[2] = f.x; d[3] = f.z;
        } else {
            for (int i = 0; i < 4; ++i) {
                s[i] = (i < n) ? ei[2 * (size_t)(e0 + i)] : 0;
                d[i] = (i < n) ? ei[2 * (size_t)(E + e0 + i)] : 0;
            }
        }
    } else {
        if (n == 4 && (E & 3) == 0) {
            const int4 a = *(const int4*)(ei + e0);
            const int4 c = *(const int4*)(ei + E + e0);
            s[0] = a.x; s[1] = a.y; s[2] = a.z; s[3] = a.w;
            d[0] = c.x; d[1] = c.y; d[2] = c.z; d[3] = c.w;
        } else {
            for (int i = 0; i < 4; ++i) {
                s[i] = (i < n) ? ei[e0 + i] : 0;
                d[i] = (i < n) ? ei[E + e0 + i] : 0;
            }
        }
    }
    int p[4];
#pragma unroll
    for (int i = 0; i < 4; ++i) {
        if (i < n) {
            int dd = d[i]; dd = (dd < 0) ? 0 : (dd >= Nn ? Nn - 1 : dd);
            p[i] = atomicAdd(&cursor[dd], 1);
        }
    }
#pragma unroll
    for (int i = 0; i < 4; ++i) {
        if (i < n) {
            int ss = s[i]; ss = (ss < 0) ? 0 : (ss >= Nn ? Nn - 1 : ss);
            srcs[p[i]] = (ushort_t)ss;
        }
    }
}

// ---------------- fused layer: gather-aggregate into LDS, then GEMM + bias + ELU ----------------
// R2 post-mortem: agg is memory-SUBSYSTEM-throughput-bound (halving gather instrs
// changed nothing; FETCH constant 174MB at 3 TB/s). gemm is MFMA-heavy/memory-light.
// Running them serially wastes the complementary profiles -> FUSE per layer:
//   block bm owns nodes [bm*64, bm*64+64).
//   Phase A: 4 waves aggregate 16 nodes each, half-wave split (lanes 0-31 = even
//     edges, 32-63 = odd; lane hl covers dims [8hl,8hl+8)); combine via shfl_xor(32);
//     half 0 writes the row into the GEMM A-tile layout directly:
//     As[(hl>>2)*64 + row][(hl&3)*8] (ds_write_b128).
//   Phase B: unchanged 2-phase GEMM (agg tiles ks0-7 already in LDS; restage root
//     half via gload_lds16; 4x4 MFMA frags; bias+ELU epilogue).
// Benefits: aggbuf round-trip deleted (-37.5MB/layer), 3 fewer launches, and with
// 3 blocks/CU the gather stalls of one block overlap other blocks' MFMA phase.

template <bool OUT_F32>
__global__ __launch_bounds__(256, 3)
void layer_kernel(const ushort_t* __restrict__ xin, const int* __restrict__ row_ptr,
                  const ushort_t* __restrict__ srcs, const ushort_t* __restrict__ Bp,
                  const float* __restrict__ bias, void* __restrict__ outp, int Nn) {
    __shared__ __align__(16) ushort_t As[8 * 64 * 32];   // 32 KB
    const int t = threadIdx.x;
    const int w = t >> 6, l = t & 63;
    const int bm = blockIdx.x;

    // ---- phase A: aggregate this block's 64 nodes into As (frag-tile layout) ----
    const int half = l >> 5;                 // 0/1: even/odd edges of the node
    const int hl   = l & 31;                 // dim chunk: dims [8*hl, 8*hl+8)
    const size_t goff = (size_t)hl * 8;
    // LDS element for (row, dim-chunk hl): As[((hl>>2)*64 + row)*32 + (hl&3)*8]
    ushort_t* ldsCol = &As[((hl >> 2) * 64) * 32 + (hl & 3) * 8];
    const int rowbase = w * 16;
    const int nbase = bm * 64 + rowbase;
#pragma unroll 1
    for (int i = 0; i < 16; ++i) {
        const int node = nbase + i;
        float a[8] = {};
        if (node < Nn) {
            const int beg = row_ptr[node], end = row_ptr[node + 1];
            const int deg = end - beg;
            int e = half;
            for (; e + 6 < deg; e += 8) {     // 4 edges per half per iter = 8/wave
                const int s0 = srcs[beg + e];
                const int s1 = srcs[beg + e + 2];
                const int s2 = srcs[beg + e + 4];
                const int s3 = srcs[beg + e + 6];
                const short8 v0 = *(const short8*)(xin + (size_t)s0 * DIM + goff);
                const short8 v1 = *(const short8*)(xin + (size_t)s1 * DIM + goff);
                const short8 v2 = *(const short8*)(xin + (size_t)s2 * DIM + goff);
                const short8 v3 = *(const short8*)(xin + (size_t)s3 * DIM + goff);
#pragma unroll
                for (int j = 0; j < 8; ++j) {
                    a[j] += bf2f((ushort_t)v0[j]);
                    a[j] += bf2f((ushort_t)v1[j]);
                    a[j] += bf2f((ushort_t)v2[j]);
                    a[j] += bf2f((ushort_t)v3[j]);
                }
            }
            for (; e < deg; e += 2) {
                const int s = srcs[beg + e];
                const short8 v = *(const short8*)(xin + (size_t)s * DIM + goff);
#pragma unroll
                for (int j = 0; j < 8; ++j) a[j] += bf2f((ushort_t)v[j]);
            }
            // combine halves (lane pairs with lane^32, same dim chunk)
#pragma unroll
            for (int j = 0; j < 8; ++j) a[j] += __shfl_xor(a[j], 32, 64);
        }
        if (half == 0) {
            short8 o;
#pragma unroll
            for (int j = 0; j < 8; ++j) o[j] = (short)f2bf(a[j]);
            *(short8*)(ldsCol + (rowbase + i) * 32) = o;
        }
    }
    __syncthreads();                          // all 64 agg rows staged

    // ---- phase B1: GEMM over agg half (ks 0..7), A from LDS, B direct global ----
    f32x4 acc[4][4] = {};
    const int mrow = l & 15;
    const int koff = (l >> 4) * 8;
    const ushort_t* BpW = Bp + ((size_t)(w * 4) * 64 + l) * 8;   // nt0 = w*4
    // strides in halves: ks -> 16*64*8 = 8192, nt -> 64*8 = 512

#pragma unroll 4
    for (int ks = 0; ks < 8; ++ks) {
        short8 bf0 = *(const short8*)(BpW + (size_t)ks * 8192 + 0 * 512);
        short8 bf1 = *(const short8*)(BpW + (size_t)ks * 8192 + 1 * 512);
        short8 bf2 = *(const short8*)(BpW + (size_t)ks * 8192 + 2 * 512);
        short8 bf3 = *(const short8*)(BpW + (size_t)ks * 8192 + 3 * 512);
        short8 af[4];
#pragma unroll
        for (int mi = 0; mi < 4; ++mi)
            af[mi] = *(const short8*)&As[(ks * 64 + mrow + mi * 16) * 32 + koff];
#pragma unroll
        for (int mi = 0; mi < 4; ++mi) {
            acc[mi][0] = __builtin_amdgcn_mfma_f32_16x16x32_bf16(af[mi], bf0, acc[mi][0], 0, 0, 0);
            acc[mi][1] = __builtin_amdgcn_mfma_f32_16x16x32_bf16(af[mi], bf1, acc[mi][1], 0, 0, 0);
            acc[mi][2] = __builtin_amdgcn_mfma_f32_16x16x32_bf16(af[mi], bf2, acc[mi][2], 0, 0, 0);
            acc[mi][3] = __builtin_amdgcn_mfma_f32_16x16x32_bf16(af[mi], bf3, acc[mi][3], 0, 0, 0);
        }
    }
    __syncthreads();   // all waves done reading agg tiles

    // ---- phase B2: restage root half into the same 32KB, compute ks 8..15 ----
    const int sub = l >> 2;                 // row-within-16
    const int kq  = l & 3;                  // 16B chunk within 64B tile-row
    const int arow = w * 16 + sub;
    int ga = bm * 64 + arow; if (ga > Nn - 1) ga = Nn - 1;
    const ushort_t* axRow = xin + (size_t)ga * DIM + kq * 8;
    ushort_t* AsW = &As[(w * 16) * 32];     // + lane*16B implicit per tile
#pragma unroll
    for (int ks = 0; ks < 8; ++ks)
        gload_lds16(axRow + ks * 32, AsW + ks * (64 * 32));
    __syncthreads();

#pragma unroll 4
    for (int ks = 8; ks < 16; ++ks) {
        short8 bf0 = *(const short8*)(BpW + (size_t)ks * 8192 + 0 * 512);
        short8 bf1 = *(const short8*)(BpW + (size_t)ks * 8192 + 1 * 512);
        short8 bf2 = *(const short8*)(BpW + (size_t)ks * 8192 + 2 * 512);
        short8 bf3 = *(const short8*)(BpW + (size_t)ks * 8192 + 3 * 512);
        short8 af[4];
#pragma unroll
        for (int mi = 0; mi < 4; ++mi)
            af[mi] = *(const short8*)&As[((ks - 8) * 64 + mrow + mi * 16) * 32 + koff];
#pragma unroll
        for (int mi = 0; mi < 4; ++mi) {
            acc[mi][0] = __builtin_amdgcn_mfma_f32_16x16x32_bf16(af[mi], bf0, acc[mi][0], 0, 0, 0);
            acc[mi][1] = __builtin_amdgcn_mfma_f32_16x16x32_bf16(af[mi], bf1, acc[mi][1], 0, 0, 0);
            acc[mi][2] = __builtin_amdgcn_mfma_f32_16x16x32_bf16(af[mi], bf2, acc[mi][2], 0, 0, 0);
            acc[mi][3] = __builtin_amdgcn_mfma_f32_16x16x32_bf16(af[mi], bf3, acc[mi][3], 0, 0, 0);
        }
    }

    // epilogue: bias + ELU; C/D layout col=lane&15, row=(lane>>4)*4+reg
    const int col0 = w * 64 + (l & 15);
    const int rb   = bm * 64 + ((l >> 4) << 2);
    float bv[4];
#pragma unroll
    for (int ni = 0; ni < 4; ++ni) bv[ni] = bias[col0 + ni * 16];
#pragma unroll
    for (int mi = 0; mi < 4; ++mi) {
#pragma unroll
        for (int r = 0; r < 4; ++r) {
            int node = rb + mi * 16 + r;
            if (node < Nn) {
#pragma unroll
                for (int ni = 0; ni < 4; ++ni) {
                    float v = acc[mi][ni][r] + bv[ni];
                    v = v > 0.f ? v : (__expf(v) - 1.f);
                    if (OUT_F32)
                        ((float*)outp)[(size_t)node * DIM + col0 + ni * 16] = v;
                    else
                        ((ushort_t*)outp)[(size_t)node * DIM + col0 + ni * 16] = f2bf(v);
                }
            }
        }
    }
}

// ---------------- launcher ----------------
// fp32 in / fp32 out per the reference dtypes. Internals in bf16.
// d_out hosts xb and h1 (both dead before layer-3 fp32 overwrite).

extern "C" void kernel_launch(void* const* d_in, const int* in_sizes, int n_in,
                              void* d_out, int out_size, void* d_ws, size_t ws_size,
                              hipStream_t stream) {
    const float* x  = (const float*)d_in[0];
    const int*   ei = (const int*)d_in[1];
    const float* Wrel[3] = { (const float*)d_in[2], (const float*)d_in[5], (const float*)d_in[8] };
    const float* bias[3] = { (const float*)d_in[3], (const float*)d_in[6], (const float*)d_in[9] };
    const float* Wroot[3]= { (const float*)d_in[4], (const float*)d_in[7], (const float*)d_in[10] };

    const int Nn = in_sizes[0] / DIM;      // 50000
    const int E  = in_sizes[1] / 2;        // 800000

    char* ws = (char*)d_ws;
    size_t off = 0;
    auto alloc = [&](size_t bytes) {
        char* p = ws + off;
        off = (off + bytes + 1023) & ~(size_t)1023;
        return p;
    };
    int* flag     = (int*)alloc(4);
    int* deg      = (int*)alloc((size_t)Nn * 4);
    int* row_ptr  = (int*)alloc((size_t)(Nn + 1) * 4);
    int* cursor   = (int*)alloc((size_t)Nn * 4);
    int* partials = (int*)alloc(64 * 4);
    ushort_t* srcs= (ushort_t*)alloc((size_t)E * 2);                // uint16 srcs
    ushort_t* Wt  = (ushort_t*)alloc((size_t)3 * DIM * KDIM * 2);   // 3 layers, frag-tile packed
    ushort_t* h2     = (ushort_t*)alloc((size_t)Nn * DIM * 2);
    (void)ws_size; (void)n_in; (void)out_size;

    ushort_t* xb = (ushort_t*)d_out;            // bf16 x copy (d_out lower half)
    ushort_t* h1 = xb + (size_t)Nn * DIM;       // bf16 hidden-1 (d_out upper half)

    // 1) probe + prep (convert | pack | hist) + scan + fill
    const int n4 = Nn * DIM / 4;
    const int cb = (n4 + 255) / 256;                     // 12500
    const int pb = (3 * DIM * KDIM + 255) / 256;         // 1536
    const int eq = (E + 3) / 4;                          // edge quads
    const int hb = (eq + 255) / 256;                     // 782 (hist + fill blocks)
    const int nb = (Nn + 1023) / 1024;                   // 49 scan blocks

    detect_kernel<<<1, 256, 0, stream>>>(ei, flag);
    hipMemsetAsync(deg, 0, (size_t)Nn * 4, stream);
    prep_kernel<<<cb + pb + hb, 256, 0, stream>>>(
        x, xb, n4, cb,
        Wrel[0], Wroot[0], Wrel[1], Wroot[1], Wrel[2], Wroot[2], Wt, pb,
        ei, flag, deg, E, Nn);
    scan1_kernel<<<nb, 256, 0, stream>>>(deg, partials, Nn);
    scan3_kernel<<<nb, 256, 0, stream>>>(deg, partials, row_ptr, cursor, Nn, E);
    fill_kernel<<<hb, 256, 0, stream>>>(ei, flag, cursor, srcs, E, Nn);

    // 2) three fused GraphConv layers (gather+aggregate+GEMM+ELU per kernel)
    const int gBlocks = (Nn + 63) / 64;                  // 782

    layer_kernel<false><<<gBlocks, 256, 0, stream>>>(xb, row_ptr, srcs, Wt, bias[0], h1, Nn);
    layer_kernel<false><<<gBlocks, 256, 0, stream>>>(h1, row_ptr, srcs, Wt + DIM * KDIM, bias[1], h2, Nn);
    layer_kernel<true><<<gBlocks, 256, 0, stream>>>(h2, row_ptr, srcs, Wt + 2 * DIM * KDIM, bias[2], d_out, Nn);
}

// Round 4
// 414.902 us; speedup vs baseline: 1.1173x; 1.0375x over previous
//
#include <hip/hip_runtime.h>
#include <hip/hip_bf16.h>

// Problem constants (shapes fixed by the reference)
#define DIM 256          // feature dim (D == H == 256)
#define KDIM 512         // fused K = D(agg) + D(root)

typedef unsigned short ushort_t;
typedef __attribute__((ext_vector_type(8))) short short8;   // 8 x bf16 (4 VGPRs) MFMA A/B frag
typedef __attribute__((ext_vector_type(4))) float f32x4;    // MFMA C/D frag

__device__ __forceinline__ float bf2f(ushort_t u) {
    union { unsigned int i; float f; } c; c.i = ((unsigned int)u) << 16; return c.f;
}
__device__ __forceinline__ ushort_t f2bf(float f) {
    unsigned int x = __float_as_uint(f);
    unsigned int r = (x + 0x7fffu + ((x >> 16) & 1u)) >> 16;
    return (ushort_t)r;
}

// async global->LDS, 16B/lane; LDS dest = wave-uniform base + lane*16
__device__ __forceinline__ void gload_lds16(const ushort_t* g, ushort_t* l) {
    __builtin_amdgcn_global_load_lds(
        (const __attribute__((address_space(1))) unsigned int*)g,
        (__attribute__((address_space(3))) unsigned int*)l, 16, 0, 0);
}

// ---------------- edge_index dtype probe (ONCE; flag read is scalar thereafter) ----------------
__global__ void detect_kernel(const int* __restrict__ ei, int* __restrict__ flag) {
    __shared__ int any;
    if (threadIdx.x == 0) any = 0;
    __syncthreads();
    if (ei[2 * threadIdx.x + 1] != 0) atomicOr(&any, 1);
    __syncthreads();
    if (threadIdx.x == 0) *flag = (any == 0) ? 1 : 0;   // 1 => int64 layout
}

// ---------------- prep: convert x->bf16 | pack 3 weight sets (frag tiles) | histogram ----------------
// B pack layout per layer: Bp[ks][nt][lane][h]  (16*16*64*8 halves = 256 KB)
//   n = nt*16 + (lane&15),  k = ks*32 + (lane>>4)*8 + h
// => wave B-frag (ks, nt) is ONE contiguous 1KB block, coalesced global->VGPR.
// Histogram branch: 4 edges/thread, coalesced int4 loads, 4 independent atomics.

__global__ __launch_bounds__(256)
void prep_kernel(const float* __restrict__ x, ushort_t* __restrict__ xb, int n4, int cb,
                 const float* __restrict__ W0r, const float* __restrict__ W0o,
                 const float* __restrict__ W1r, const float* __restrict__ W1o,
                 const float* __restrict__ W2r, const float* __restrict__ W2o,
                 ushort_t* __restrict__ Wt, int pb,
                 const int* __restrict__ ei, const int* __restrict__ flag,
                 int* __restrict__ deg, int E, int Nn) {
    int bid = blockIdx.x;
    int t = threadIdx.x;
    if (bid < cb) {
        int i = bid * 256 + t;
        if (i < n4) {
            const float4 v = *(const float4*)(x + (size_t)i * 4);
            ushort4 o;
            o.x = f2bf(v.x); o.y = f2bf(v.y); o.z = f2bf(v.z); o.w = f2bf(v.w);
            *(ushort4*)(xb + (size_t)i * 4) = o;
        }
    } else if (bid < cb + pb) {
        int id = (bid - cb) * 256 + t;            // over 3*131072
        int layer = id >> 17;
        int rem = id & 131071;
        int ks   = rem >> 13;                     // 8192 per ks
        int nt   = (rem >> 9) & 15;
        int lane = (rem >> 3) & 63;
        int h    = rem & 7;
        int n = nt * 16 + (lane & 15);
        int k = ks * 32 + ((lane >> 4) << 3) + h;
        const float* Wr = (layer == 0) ? W0r : (layer == 1) ? W1r : W2r;
        const float* Wo = (layer == 0) ? W0o : (layer == 1) ? W1o : W2o;
        float v = (k < DIM) ? Wr[k * DIM + n] : Wo[(k - DIM) * DIM + n];
        Wt[id] = f2bf(v);
    } else {
        int q = (bid - cb - pb) * 256 + t;        // quad index: 4 edges each
        int e0 = q * 4;
        if (e0 < E) {
            const int is64 = *flag;               // wave-uniform scalar load
            const int n = (E - e0 < 4) ? (E - e0) : 4;
            int d[4];
            if (is64) {
                if (n == 4 && (E & 1) == 0) {
                    const int4 c = *(const int4*)(ei + 2 * (size_t)(E + e0));
                    const int4 f = *(const int4*)(ei + 2 * (size_t)(E + e0) + 4);
                    d[0] = c.x; d[1] = c.z; d[2] = f.x; d[3] = f.z;
                } else {
                    for (int i = 0; i < 4; ++i) d[i] = (i < n) ? ei[2 * (size_t)(E + e0 + i)] : 0;
                }
            } else {
                if (n == 4 && (E & 3) == 0) {
                    const int4 c = *(const int4*)(ei + E + e0);
                    d[0] = c.x; d[1] = c.y; d[2] = c.z; d[3] = c.w;
                } else {
                    for (int i = 0; i < 4; ++i) d[i] = (i < n) ? ei[E + e0 + i] : 0;
                }
            }
#pragma unroll
            for (int i = 0; i < 4; ++i) {
                if (i < n) {
                    int dd = d[i]; dd = (dd < 0) ? 0 : (dd >= Nn ? Nn - 1 : dd);
                    atomicAdd(&deg[dd], 1);
                }
            }
        }
    }
}

// ---------------- scan: deg -> row_ptr/cursor (2 kernels) ----------------

__global__ __launch_bounds__(256)
void scan1_kernel(const int* __restrict__ deg, int* __restrict__ partials, int Nn) {
    __shared__ int red[256];
    int t = threadIdx.x;
    int base = blockIdx.x * 1024 + t * 4;
    int s = 0;
    if (base + 3 < Nn) {
        const int4 v = *(const int4*)(deg + base);
        s = v.x + v.y + v.z + v.w;
    } else {
        for (int i = 0; i < 4; ++i) if (base + i < Nn) s += deg[base + i];
    }
    red[t] = s;
    __syncthreads();
    for (int off = 128; off > 0; off >>= 1) {
        if (t < off) red[t] += red[t + off];
        __syncthreads();
    }
    if (t == 0) partials[blockIdx.x] = red[0];
}

__global__ __launch_bounds__(256)
void scan3_kernel(const int* __restrict__ deg, const int* __restrict__ partials,
                  int* __restrict__ row_ptr, int* __restrict__ cursor, int Nn, int E) {
    __shared__ int sdata[256];
    int t = threadIdx.x;
    int pref = 0;
    for (int i = 0; i < blockIdx.x; ++i) pref += partials[i];   // <=49 L2-hot loads
    int base = blockIdx.x * 1024 + t * 4;
    int d0 = 0, d1 = 0, d2 = 0, d3 = 0;
    if (base + 3 < Nn) {
        const int4 v = *(const int4*)(deg + base);
        d0 = v.x; d1 = v.y; d2 = v.z; d3 = v.w;
    } else {
        if (base + 0 < Nn) d0 = deg[base + 0];
        if (base + 1 < Nn) d1 = deg[base + 1];
        if (base + 2 < Nn) d2 = deg[base + 2];
        if (base + 3 < Nn) d3 = deg[base + 3];
    }
    int tsum = d0 + d1 + d2 + d3;
    sdata[t] = tsum;
    __syncthreads();
    for (int off = 1; off < 256; off <<= 1) {
        int u = (t >= off) ? sdata[t - off] : 0;
        __syncthreads();
        sdata[t] += u;
        __syncthreads();
    }
    int p0 = sdata[t] - tsum + pref;
    int p1 = p0 + d0, p2 = p1 + d1, p3 = p2 + d2;
    if (base + 3 < Nn) {
        *(int4*)(row_ptr + base) = make_int4(p0, p1, p2, p3);
        *(int4*)(cursor  + base) = make_int4(p0, p1, p2, p3);
    } else {
        if (base + 0 < Nn) { row_ptr[base + 0] = p0; cursor[base + 0] = p0; }
        if (base + 1 < Nn) { row_ptr[base + 1] = p1; cursor[base + 1] = p1; }
        if (base + 2 < Nn) { row_ptr[base + 2] = p2; cursor[base + 2] = p2; }
        if (base + 3 < Nn) { row_ptr[base + 3] = p3; cursor[base + 3] = p3; }
    }
    if (blockIdx.x == 0 && t == 0) row_ptr[Nn] = E;
}

// ---------------- fill: 4 edges/thread, int4-coalesced ei loads, uint16 srcs ----------------

__global__ __launch_bounds__(256)
void fill_kernel(const int* __restrict__ ei, const int* __restrict__ flag,
                 int* __restrict__ cursor, ushort_t* __restrict__ srcs, int E, int Nn) {
    int q = blockIdx.x * blockDim.x + threadIdx.x;
    int e0 = q * 4;
    if (e0 >= E) return;
    const int is64 = *flag;                       // wave-uniform scalar load
    const int n = (E - e0 < 4) ? (E - e0) : 4;
    int s[4], d[4];
    if (is64) {
        if (n == 4 && (E & 1) == 0) {
            const int4 a = *(const int4*)(ei + 2 * (size_t)e0);
            const int4 b = *(const int4*)(ei + 2 * (size_t)e0 + 4);
            const int4 c = *(const int4*)(ei + 2 * (size_t)(E + e0));
            const int4 f = *(const int4*)(ei + 2 * (size_t)(E + e0) + 4);
            s[0] = a.x; s[1] = a.z; s[2] = b.x; s[3] = b.z;
            d[0] = c.x; d[1] = c.z; d[2] = f.x; d[3] = f.z;
        } else {
            for (int i = 0; i < 4; ++i) {
                s[i] = (i < n) ? ei[2 * (size_t)(e0 + i)] : 0;
                d[i] = (i < n) ? ei[2 * (size_t)(E + e0 + i)] : 0;
            }
        }
    } else {
        if (n == 4 && (E & 3) == 0) {
            const int4 a = *(const int4*)(ei + e0);
            const int4 c = *(const int4*)(ei + E + e0);
            s[0] = a.x; s[1] = a.y; s[2] = a.z; s[3] = a.w;
            d[0] = c.x; d[1] = c.y; d[2] = c.z; d[3] = c.w;
        } else {
            for (int i = 0; i < 4; ++i) {
                s[i] = (i < n) ? ei[e0 + i] : 0;
                d[i] = (i < n) ? ei[E + e0 + i] : 0;
            }
        }
    }
    int p[4];
#pragma unroll
    for (int i = 0; i < 4; ++i) {
        if (i < n) {
            int dd = d[i]; dd = (dd < 0) ? 0 : (dd >= Nn ? Nn - 1 : dd);
            p[i] = atomicAdd(&cursor[dd], 1);
        }
    }
#pragma unroll
    for (int i = 0; i < 4; ++i) {
        if (i < n) {
            int ss = s[i]; ss = (ss < 0) ? 0 : (ss >= Nn ? Nn - 1 : ss);
            srcs[p[i]] = (ushort_t)ss;
        }
    }
}

// ---------------- fused layer: gather-aggregate into LDS, then GEMM + bias + ELU ----------------
// R3 post-mortem: layer_kernel sits exactly at its achieved-BW limit
// (239MB / 2.87TB/s = 83.3us = measured), and achieved BW dropped from the
// standalone agg's 3.5TB/s because only 12 waves/CU (3 blocks x 4 waves,
// occupancy 27.5%) issue gathers. Gather BW is concave in concurrent waves:
// BW(32w)=3.5, BW(12w)=2.87. Fix: same BM=64/BN=256 tile, but 512 threads /
// 8 waves per block -> 24 waves/CU at the same 3 blocks/CU (LDS still 32KB).
// Per-wave shrinks: 8 agg nodes, 2 B-frag columns (acc 4x2 = 32 AGPR), so
// __launch_bounds__(512,6) (~85 reg cap) should hold without spill.

template <bool OUT_F32>
__global__ __launch_bounds__(512, 6)
void layer_kernel(const ushort_t* __restrict__ xin, const int* __restrict__ row_ptr,
                  const ushort_t* __restrict__ srcs, const ushort_t* __restrict__ Bp,
                  const float* __restrict__ bias, void* __restrict__ outp, int Nn) {
    __shared__ __align__(16) ushort_t As[8 * 64 * 32];   // 32 KB
    const int t = threadIdx.x;
    const int w = t >> 6, l = t & 63;    // 8 waves
    const int bm = blockIdx.x;

    // ---- phase A: aggregate this block's 64 nodes into As (frag-tile layout) ----
    // wave w handles rows [w*8, w*8+8); half-wave split over even/odd edges.
    const int half = l >> 5;                 // 0/1: even/odd edges of the node
    const int hl   = l & 31;                 // dim chunk: dims [8*hl, 8*hl+8)
    const size_t goff = (size_t)hl * 8;
    // LDS element for (row, dim-chunk hl): As[((hl>>2)*64 + row)*32 + (hl&3)*8]
    ushort_t* ldsCol = &As[((hl >> 2) * 64) * 32 + (hl & 3) * 8];
    const int rowbase = w * 8;
    const int nbase = bm * 64 + rowbase;
#pragma unroll 1
    for (int i = 0; i < 8; ++i) {
        const int node = nbase + i;
        float a[8] = {};
        if (node < Nn) {
            const int beg = row_ptr[node], end = row_ptr[node + 1];
            const int deg = end - beg;
            int e = half;
            for (; e + 6 < deg; e += 8) {     // 4 edges per half per iter = 8/wave
                const int s0 = srcs[beg + e];
                const int s1 = srcs[beg + e + 2];
                const int s2 = srcs[beg + e + 4];
                const int s3 = srcs[beg + e + 6];
                const short8 v0 = *(const short8*)(xin + (size_t)s0 * DIM + goff);
                const short8 v1 = *(const short8*)(xin + (size_t)s1 * DIM + goff);
                const short8 v2 = *(const short8*)(xin + (size_t)s2 * DIM + goff);
                const short8 v3 = *(const short8*)(xin + (size_t)s3 * DIM + goff);
#pragma unroll
                for (int j = 0; j < 8; ++j) {
                    a[j] += bf2f((ushort_t)v0[j]);
                    a[j] += bf2f((ushort_t)v1[j]);
                    a[j] += bf2f((ushort_t)v2[j]);
                    a[j] += bf2f((ushort_t)v3[j]);
                }
            }
            for (; e < deg; e += 2) {
                const int s = srcs[beg + e];
                const short8 v = *(const short8*)(xin + (size_t)s * DIM + goff);
#pragma unroll
                for (int j = 0; j < 8; ++j) a[j] += bf2f((ushort_t)v[j]);
            }
            // combine halves (lane pairs with lane^32, same dim chunk)
#pragma unroll
            for (int j = 0; j < 8; ++j) a[j] += __shfl_xor(a[j], 32, 64);
        }
        if (half == 0) {
            short8 o;
#pragma unroll
            for (int j = 0; j < 8; ++j) o[j] = (short)f2bf(a[j]);
            *(short8*)(ldsCol + (rowbase + i) * 32) = o;
        }
    }
    __syncthreads();                          // all 64 agg rows staged

    // ---- phase B1: GEMM over agg half (ks 0..7), A from LDS, B direct global ----
    // wave w covers output cols [w*32, w*32+32) -> nt = w*2 + {0,1}
    f32x4 acc[4][2] = {};
    const int mrow = l & 15;
    const int koff = (l >> 4) * 8;
    const ushort_t* BpW = Bp + ((size_t)(w * 2) * 64 + l) * 8;   // nt0 = w*2
    // strides in halves: ks -> 16*64*8 = 8192, nt -> 64*8 = 512

#pragma unroll 4
    for (int ks = 0; ks < 8; ++ks) {
        short8 bf0 = *(const short8*)(BpW + (size_t)ks * 8192 + 0 * 512);
        short8 bf1 = *(const short8*)(BpW + (size_t)ks * 8192 + 1 * 512);
        short8 af[4];
#pragma unroll
        for (int mi = 0; mi < 4; ++mi)
            af[mi] = *(const short8*)&As[(ks * 64 + mrow + mi * 16) * 32 + koff];
#pragma unroll
        for (int mi = 0; mi < 4; ++mi) {
            acc[mi][0] = __builtin_amdgcn_mfma_f32_16x16x32_bf16(af[mi], bf0, acc[mi][0], 0, 0, 0);
            acc[mi][1] = __builtin_amdgcn_mfma_f32_16x16x32_bf16(af[mi], bf1, acc[mi][1], 0, 0, 0);
        }
    }
    __syncthreads();   // all waves done reading agg tiles

    // ---- phase B2: restage root half into the same 32KB, compute ks 8..15 ----
    // 8 waves stage 8 tiles x 64 rows: wave w -> row-group rg = w&3 (16 rows),
    // tiles ks in [ (w>>2)*4, (w>>2)*4+4 ). Each gload covers 16 rows (64 lanes x 16B).
    const int sub = l >> 2;                 // row-within-16
    const int kq  = l & 3;                  // 16B chunk within 64B tile-row
    const int rg  = w & 3;
    const int ksb = (w >> 2) * 4;
    const int arow = rg * 16 + sub;
    int ga = bm * 64 + arow; if (ga > Nn - 1) ga = Nn - 1;
    const ushort_t* axRow = xin + (size_t)ga * DIM + kq * 8;
    ushort_t* AsW = &As[(rg * 16) * 32];    // + lane*16B implicit per tile
#pragma unroll
    for (int j = 0; j < 4; ++j)
        gload_lds16(axRow + (ksb + j) * 32, AsW + (ksb + j) * (64 * 32));
    __syncthreads();

#pragma unroll 4
    for (int ks = 8; ks < 16; ++ks) {
        short8 bf0 = *(const short8*)(BpW + (size_t)ks * 8192 + 0 * 512);
        short8 bf1 = *(const short8*)(BpW + (size_t)ks * 8192 + 1 * 512);
        short8 af[4];
#pragma unroll
        for (int mi = 0; mi < 4; ++mi)
            af[mi] = *(const short8*)&As[((ks - 8) * 64 + mrow + mi * 16) * 32 + koff];
#pragma unroll
        for (int mi = 0; mi < 4; ++mi) {
            acc[mi][0] = __builtin_amdgcn_mfma_f32_16x16x32_bf16(af[mi], bf0, acc[mi][0], 0, 0, 0);
            acc[mi][1] = __builtin_amdgcn_mfma_f32_16x16x32_bf16(af[mi], bf1, acc[mi][1], 0, 0, 0);
        }
    }

    // epilogue: bias + ELU; C/D layout col=lane&15, row=(lane>>4)*4+reg
    const int col0 = w * 32 + (l & 15);
    const int rb   = bm * 64 + ((l >> 4) << 2);
    float bv[2];
#pragma unroll
    for (int ni = 0; ni < 2; ++ni) bv[ni] = bias[col0 + ni * 16];
#pragma unroll
    for (int mi = 0; mi < 4; ++mi) {
#pragma unroll
        for (int r = 0; r < 4; ++r) {
            int node = rb + mi * 16 + r;
            if (node < Nn) {
#pragma unroll
                for (int ni = 0; ni < 2; ++ni) {
                    float v = acc[mi][ni][r] + bv[ni];
                    v = v > 0.f ? v : (__expf(v) - 1.f);
                    if (OUT_F32)
                        ((float*)outp)[(size_t)node * DIM + col0 + ni * 16] = v;
                    else
                        ((ushort_t*)outp)[(size_t)node * DIM + col0 + ni * 16] = f2bf(v);
                }
            }
        }
    }
}

// ---------------- launcher ----------------
// fp32 in / fp32 out per the reference dtypes. Internals in bf16.
// d_out hosts xb and h1 (both dead before layer-3 fp32 overwrite).

extern "C" void kernel_launch(void* const* d_in, const int* in_sizes, int n_in,
                              void* d_out, int out_size, void* d_ws, size_t ws_size,
                              hipStream_t stream) {
    const float* x  = (const float*)d_in[0];
    const int*   ei = (const int*)d_in[1];
    const float* Wrel[3] = { (const float*)d_in[2], (const float*)d_in[5], (const float*)d_in[8] };
    const float* bias[3] = { (const float*)d_in[3], (const float*)d_in[6], (const float*)d_in[9] };
    const float* Wroot[3]= { (const float*)d_in[4], (const float*)d_in[7], (const float*)d_in[10] };

    const int Nn = in_sizes[0] / DIM;      // 50000
    const int E  = in_sizes[1] / 2;        // 800000

    char* ws = (char*)d_ws;
    size_t off = 0;
    auto alloc = [&](size_t bytes) {
        char* p = ws + off;
        off = (off + bytes + 1023) & ~(size_t)1023;
        return p;
    };
    int* flag     = (int*)alloc(4);
    int* deg      = (int*)alloc((size_t)Nn * 4);
    int* row_ptr  = (int*)alloc((size_t)(Nn + 1) * 4);
    int* cursor   = (int*)alloc((size_t)Nn * 4);
    int* partials = (int*)alloc(64 * 4);
    ushort_t* srcs= (ushort_t*)alloc((size_t)E * 2);                // uint16 srcs
    ushort_t* Wt  = (ushort_t*)alloc((size_t)3 * DIM * KDIM * 2);   // 3 layers, frag-tile packed
    ushort_t* h2     = (ushort_t*)alloc((size_t)Nn * DIM * 2);
    (void)ws_size; (void)n_in; (void)out_size;

    ushort_t* xb = (ushort_t*)d_out;            // bf16 x copy (d_out lower half)
    ushort_t* h1 = xb + (size_t)Nn * DIM;       // bf16 hidden-1 (d_out upper half)

    // 1) probe + prep (convert | pack | hist) + scan + fill
    const int n4 = Nn * DIM / 4;
    const int cb = (n4 + 255) / 256;                     // 12500
    const int pb = (3 * DIM * KDIM + 255) / 256;         // 1536
    const int eq = (E + 3) / 4;                          // edge quads
    const int hb = (eq + 255) / 256;                     // 782 (hist + fill blocks)
    const int nb = (Nn + 1023) / 1024;                   // 49 scan blocks

    detect_kernel<<<1, 256, 0, stream>>>(ei, flag);
    hipMemsetAsync(deg, 0, (size_t)Nn * 4, stream);
    prep_kernel<<<cb + pb + hb, 256, 0, stream>>>(
        x, xb, n4, cb,
        Wrel[0], Wroot[0], Wrel[1], Wroot[1], Wrel[2], Wroot[2], Wt, pb,
        ei, flag, deg, E, Nn);
    scan1_kernel<<<nb, 256, 0, stream>>>(deg, partials, Nn);
    scan3_kernel<<<nb, 256, 0, stream>>>(deg, partials, row_ptr, cursor, Nn, E);
    fill_kernel<<<hb, 256, 0, stream>>>(ei, flag, cursor, srcs, E, Nn);

    // 2) three fused GraphConv layers (gather+aggregate+GEMM+ELU per kernel)
    const int gBlocks = (Nn + 63) / 64;                  // 782

    layer_kernel<false><<<gBlocks, 512, 0, stream>>>(xb, row_ptr, srcs, Wt, bias[0], h1, Nn);
    layer_kernel<false><<<gBlocks, 512, 0, stream>>>(h1, row_ptr, srcs, Wt + DIM * KDIM, bias[1], h2, Nn);
    layer_kernel<true><<<gBlocks, 512, 0, stream>>>(h2, row_ptr, srcs, Wt + 2 * DIM * KDIM, bias[2], d_out, Nn);
}